// Round 13
// baseline (261.758 us; speedup 1.0000x reference)
//
#include <hip/hip_runtime.h>
#include <hip/hip_bf16.h>
#include <math.h>

typedef _Float16 half8 __attribute__((ext_vector_type(8)));
typedef _Float16 half4v __attribute__((ext_vector_type(4)));
typedef float f32x4 __attribute__((ext_vector_type(4)));

#define NB 8
#define NAA 20
#define ND 16
#define NL 512
#define NC2 4096
#define NC 2048
#define NF 12
#define NR 96      // B*F rows
#define NK 1024    // 2*L contraction for conv GEMM
#define CT 64      // c-tile (conv GEMM N-tile) -> 512 blocks = 2/CU
#define KC 64      // staged K-chunk (conv GEMM)
#define LSTR 72    // LDS row stride in halves (part 1)
#define CTS 72     // convT LDS stride (halves)
#define BST2 514   // part-2 A0 stage stride (halves): row stride == 1 word mod 32
#define NCT 32     // number of c-tiles = partial count

// Raw-barrier fence: compiler memory fence + per-wave LDS drain + hw barrier.
// NO vmcnt drain -> prefetched global loads stay in flight across it (T3/T14).
#define FENCE_BARRIER()                                       \
  do {                                                        \
    asm volatile("s_waitcnt lgkmcnt(0)" ::: "memory");        \
    __builtin_amdgcn_sched_barrier(0);                        \
    __builtin_amdgcn_s_barrier();                             \
    __builtin_amdgcn_sched_barrier(0);                        \
  } while (0)

// ---------- Kernel A: G[d][r][j] = sum_n conv_w[f][n][k] * aa[b][n][d*L+s]
__global__ __launch_bounds__(256) void k_g(const float* __restrict__ aa,
                                           const float* __restrict__ conv_w,
                                           _Float16* __restrict__ G) {
  int idx = blockIdx.x * 256 + threadIdx.x;   // 16*96*1024 total
  int j  = idx & (NK - 1);
  int rd = idx >> 10;
  int r  = rd % NR;
  int d  = rd / NR;
  int k  = j >> 9;
  int s  = j & (NL - 1);
  int b  = r / NF;
  int f  = r % NF;
  const float* aap = aa + (size_t)(b * NAA) * (ND * NL) + d * NL + s;
  const float* wp  = conv_w + f * NAA * 2 + k;
  float acc = 0.f;
#pragma unroll
  for (int n = 0; n < NAA; ++n)
    acc += wp[n * 2] * aap[(size_t)n * (ND * NL)];
  G[idx] = (_Float16)acc;
}

// ---------- Fused conv+contract. CT=64 -> 512 blocks (2/CU) for TLP.
// 8 waves: part 1 wave (mh, c16) computes conv [48 x 16]; part 2 wave
// (mh, lq) computes aa2 partial [48 x 128] over the tile's 64 c.
__global__ __launch_bounds__(512) void k_fused(const float* __restrict__ adjs,
                                               const _Float16* __restrict__ G,
                                               _Float16* __restrict__ aa2p,
                                               float* __restrict__ deg) {
  __shared__ union {
    struct { _Float16 lA[NR * LSTR]; _Float16 lB[CT * LSTR]; float degp[4][16][33]; } p1;
    struct { _Float16 convT[NR * CTS]; _Float16 lB2[32 * BST2]; } p2;
  } S;

  int bid = blockIdx.x;                     // 512 blocks
  int d  = ((bid & 7) << 1) | ((bid >> 3) & 1);  // d-pair pinned per XCD slot
  int ct = bid >> 4;                        // 0..31
  int t = threadIdx.x;                      // 0..511
  int w = t >> 6;                           // 0..7
  int lane = t & 63;
  int l16 = lane & 15;
  int kg  = lane >> 4;
  int mh  = w >> 2;                         // m-half: 0..1 (48 rows each)
  int c0 = ct * CT;
  const float*    Adj = adjs + (size_t)d * NC2 * NL;   // as [2048][1024] row-major
  const _Float16* Gd  = G + (size_t)d * NR * NK;

  // ---------------- part 1: conv tile [96 x 64] ----------------
  f32x4 acc[3];
#pragma unroll
  for (int i = 0; i < 3; ++i) acc[i] = (f32x4)0.f;

  int brow = t >> 4;        // 0..31
  int col4 = t & 15;        // 0..15
  int c16  = (w & 3) * 16;  // part-1 wave c-slice

  uint2  pa[3];             // prefetched A (G) regs
  float4 pb[2];             // prefetched B (adjs) regs

  auto loadA = [&](int kc) {
#pragma unroll
    for (int i = 0; i < 3; ++i) {
      int unit = i * 512 + t;
      int row = unit >> 4, u = unit & 15;
      pa[i] = *(const uint2*)(Gd + (size_t)row * NK + kc * KC + u * 4);
    }
  };
  auto loadB = [&](int kc) {
#pragma unroll
    for (int i = 0; i < 2; ++i) {
      int row = i * 32 + brow;
      pb[i] = *(const float4*)(Adj + (size_t)(c0 + row) * NK + kc * KC + col4 * 4);
    }
  };

  loadA(0);
  loadB(0);

  for (int kc = 0; kc < NK / KC; ++kc) {
    // write prefetched regs -> LDS (reg use = implicit per-wave vmcnt wait)
#pragma unroll
    for (int i = 0; i < 3; ++i) {
      int unit = i * 512 + t;
      int row = unit >> 4, u = unit & 15;
      *(uint2*)(&S.p1.lA[row * LSTR + u * 4]) = pa[i];
    }
    float cs0 = 0, cs1 = 0, cs2 = 0, cs3 = 0;
#pragma unroll
    for (int i = 0; i < 2; ++i) {
      int row = i * 32 + brow;
      float4 v = pb[i];
      cs0 += v.x; cs1 += v.y; cs2 += v.z; cs3 += v.w;
      half4v hv = {(_Float16)v.x, (_Float16)v.y, (_Float16)v.z, (_Float16)v.w};
      *(half4v*)(&S.p1.lB[row * LSTR + col4 * 4]) = hv;
    }
    S.p1.degp[0][col4][brow] = cs0;
    S.p1.degp[1][col4][brow] = cs1;
    S.p1.degp[2][col4][brow] = cs2;
    S.p1.degp[3][col4][brow] = cs3;
    // issue next chunk's loads; they stay in flight across both barriers + MFMA
    if (kc < NK / KC - 1) {
      loadA(kc + 1);
      loadB(kc + 1);
    }
    FENCE_BARRIER();
    if (t < 64) {
      int cg = t >> 2, ci = t & 3;
      float sum = 0.f;
#pragma unroll
      for (int p = 0; p < 32; ++p) sum += S.p1.degp[ci][cg][p];
      int j = kc * KC + cg * 4 + ci;
      atomicAdd(deg + d * NL + (j & (NL - 1)), sum);
    }
#pragma unroll
    for (int ks = 0; ks < 2; ++ks) {
      int ko = ks * 32 + 8 * kg;
      half8 b0 = *(const half8*)(&S.p1.lB[(c16 + l16) * LSTR + ko]);
#pragma unroll
      for (int mf = 0; mf < 3; ++mf) {
        half8 a = *(const half8*)(&S.p1.lA[(mh * 48 + mf * 16 + l16) * LSTR + ko]);
        acc[mf] = __builtin_amdgcn_mfma_f32_16x16x32_f16(a, b0, acc[mf], 0, 0, 0);
      }
    }
    FENCE_BARRIER();
  }

  // conv tile -> LDS (c-contiguous rows for part-2 A-fragments)
#pragma unroll
  for (int mf = 0; mf < 3; ++mf)
#pragma unroll
    for (int jj = 0; jj < 4; ++jj) {
      int m  = mh * 48 + mf * 16 + kg * 4 + jj;
      S.p2.convT[m * CTS + c16 + l16] = (_Float16)acc[mf][jj];
    }

  // ---------------- part 2: aa2 partial [96 x 512] over 64 c ----------------
  int lq = w & 3;           // l-quarter (128 l)
  float4 pc[8];             // prefetched A0 regs
  auto loadC = [&](int cc2) {
#pragma unroll
    for (int i = 0; i < 8; ++i) {
      int unit = i * 512 + t;
      int c  = unit >> 7;         // 0..31
      int l4 = unit & 127;
      pc[i] = *(const float4*)(Adj + (size_t)(2 * (c0 + cc2 * 32 + c)) * NL + l4 * 4);
    }
  };
  loadC(0);                 // in flight across the convT barrier
  FENCE_BARRIER();

  f32x4 acc2[3][8];
#pragma unroll
  for (int i = 0; i < 3; ++i)
#pragma unroll
    for (int q = 0; q < 8; ++q) acc2[i][q] = (f32x4)0.f;

  for (int cc2 = 0; cc2 < 2; ++cc2) {
#pragma unroll
    for (int i = 0; i < 8; ++i) {
      int unit = i * 512 + t;
      int c  = unit >> 7;
      int l4 = unit & 127;
      float4 v = pc[i];
      half4v hv = {(_Float16)v.x, (_Float16)v.y, (_Float16)v.z, (_Float16)v.w};
      *(half4v*)(&S.p2.lB2[c * BST2 + l4 * 4]) = hv;
    }
    if (cc2 < 1) loadC(cc2 + 1);
    FENCE_BARRIER();
    half8 bfr[8];
#pragma unroll
    for (int nf = 0; nf < 8; ++nf) {
      int lcol = lq * 128 + nf * 16 + l16;
#pragma unroll
      for (int j = 0; j < 8; ++j)
        bfr[nf][j] = S.p2.lB2[(kg * 8 + j) * BST2 + lcol];
    }
#pragma unroll
    for (int mf = 0; mf < 3; ++mf) {
      half8 a = *(const half8*)(&S.p2.convT[(mh * 48 + mf * 16 + l16) * CTS + cc2 * 32 + kg * 8]);
#pragma unroll
      for (int nf = 0; nf < 8; ++nf)
        acc2[mf][nf] = __builtin_amdgcn_mfma_f32_16x16x32_f16(a, bfr[nf], acc2[mf][nf], 0, 0, 0);
    }
    FENCE_BARRIER();
  }
  _Float16* outp = aa2p + (size_t)(ct * ND + d) * NR * NL;
#pragma unroll
  for (int mf = 0; mf < 3; ++mf)
#pragma unroll
    for (int nf = 0; nf < 8; ++nf)
#pragma unroll
      for (int jj = 0; jj < 4; ++jj) {
        int m = mh * 48 + mf * 16 + kg * 4 + jj;
        int l = lq * 128 + nf * 16 + l16;
        outp[(size_t)m * NL + l] = (_Float16)acc2[mf][nf][jj];
      }
}

// ---------- Reduce: one block per (d, r): sum 32 partials, /deg, max over l
__global__ __launch_bounds__(256) void k_reduce(const _Float16* __restrict__ aa2p,
                                                const float* __restrict__ deg,
                                                float* __restrict__ dmax) {
  __shared__ float wm[4];
  int r = blockIdx.x;         // 0..95
  int d = blockIdx.y;         // 0..15
  int t = threadIdx.x;
  int w = t >> 6, lane = t & 63;
  float best = -1e30f;
#pragma unroll
  for (int rep = 0; rep < 2; ++rep) {
    int l = t + rep * 256;
    float s = 0.f;
#pragma unroll
    for (int ct = 0; ct < NCT; ++ct)
      s += (float)aa2p[((size_t)(ct * ND + d) * NR + r) * NL + l];
    best = fmaxf(best, s / deg[d * NL + l]);
  }
#pragma unroll
  for (int off = 32; off >= 1; off >>= 1)
    best = fmaxf(best, __shfl_xor(best, off));
  if (lane == 0) wm[w] = best;
  __syncthreads();
  if (t == 0)
    dmax[d * NR + r] = fmaxf(fmaxf(wm[0], wm[1]), fmaxf(wm[2], wm[3]));
}

// ---------- Out: 128 scores = dot(dmax row, lin_w) -> sigmoid
__global__ __launch_bounds__(128) void k_out(const float* __restrict__ dmax,
                                             const float* __restrict__ lin_w,
                                             float* __restrict__ out) {
  int t = threadIdx.x;        // 0..127: d = t>>3, b = t&7
  int d = t >> 3, b = t & 7;
  float s = 0.f;
#pragma unroll
  for (int f = 0; f < NF; ++f)
    s += dmax[d * NR + b * NF + f] * lin_w[f];
  out[d * NB + b] = 1.f / (1.f + expf(-s));
}

extern "C" void kernel_launch(void* const* d_in, const int* in_sizes, int n_in,
                              void* d_out, int out_size, void* d_ws, size_t ws_size,
                              hipStream_t stream) {
  const float* aa     = (const float*)d_in[0];
  const float* adjs   = (const float*)d_in[1];
  const float* conv_w = (const float*)d_in[2];
  const float* lin_w  = (const float*)d_in[3];
  float* out = (float*)d_out;

  char* ws = (char*)d_ws;
  _Float16* G    = (_Float16*)ws;                       // 3,145,728 B
  _Float16* aa2p = (_Float16*)(ws + 3145728);           // 32 fp16 partials: 50,331,648 B
  float*    deg  = (float*)(ws + 3145728 + 50331648);   // 32 KB
  float*    dmax = (float*)(ws + 3145728 + 50331648 + 32768); // 6 KB

  hipMemsetAsync(deg, 0, ND * NL * sizeof(float), stream);

  k_g<<<dim3((ND * NR * NK) / 256), 256, 0, stream>>>(aa, conv_w, G);
  k_fused<<<dim3(512), 512, 0, stream>>>(adjs, G, aa2p, deg);
  k_reduce<<<dim3(NR, ND), 256, 0, stream>>>(aa2p, deg, dmax);
  k_out<<<dim3(1), 128, 0, stream>>>(dmax, lin_w, out);
}

// Round 16
// 244.072 us; speedup vs baseline: 1.0725x; 1.0725x over previous
//
#include <hip/hip_runtime.h>
#include <hip/hip_bf16.h>
#include <math.h>

typedef _Float16 half8 __attribute__((ext_vector_type(8)));
typedef _Float16 half4v __attribute__((ext_vector_type(4)));
typedef float f32x4 __attribute__((ext_vector_type(4)));

#define NB 8
#define NAA 20
#define ND 16
#define NL 512
#define NC2 4096
#define NC 2048
#define NF 12
#define NR 96      // B*F rows
#define NK 1024    // 2*L contraction for conv GEMM
#define CT 128     // c-tile (conv GEMM N-tile)
#define KC 64      // staged K-chunk (conv GEMM)
#define LSTR 72    // LDS row stride in halves (part 1)
#define CTS 136    // convT LDS stride (halves)
#define BST2 514   // part-2 A0 stage stride (halves)
#define NCT 16     // number of c-tiles = partial count

// Raw-barrier fence: "memory"-clobbered lgkmcnt(0) + hw barrier. NO vmcnt
// drain (prefetched global loads stay in flight) and NO sched_barrier pins
// (m141: order-pinning defeats the compiler scheduler).
#define FENCE_BARRIER()                                       \
  do {                                                        \
    asm volatile("s_waitcnt lgkmcnt(0)" ::: "memory");        \
    __builtin_amdgcn_s_barrier();                             \
  } while (0)

// ---------- Kernel A: G[d][r][j] = sum_n conv_w[f][n][k] * aa[b][n][d*L+s]
__global__ __launch_bounds__(256) void k_g(const float* __restrict__ aa,
                                           const float* __restrict__ conv_w,
                                           _Float16* __restrict__ G) {
  int idx = blockIdx.x * 256 + threadIdx.x;   // 16*96*1024 total
  int j  = idx & (NK - 1);
  int rd = idx >> 10;
  int r  = rd % NR;
  int d  = rd / NR;
  int k  = j >> 9;
  int s  = j & (NL - 1);
  int b  = r / NF;
  int f  = r % NF;
  const float* aap = aa + (size_t)(b * NAA) * (ND * NL) + d * NL + s;
  const float* wp  = conv_w + f * NAA * 2 + k;
  float acc = 0.f;
#pragma unroll
  for (int n = 0; n < NAA; ++n)
    acc += wp[n * 2] * aap[(size_t)n * (ND * NL)];
  G[idx] = (_Float16)acc;
}

// ---------- Fused conv+contract, 512 threads, reg-staged prefetch across
// raw barriers (no vmcnt(0) drain). Part 1: conv tile [96 x 128].
// Part 2: partial aa2[96 x 512] over this tile's 128 c.
__global__ __launch_bounds__(512) void k_fused(const float* __restrict__ adjs,
                                               const _Float16* __restrict__ G,
                                               _Float16* __restrict__ aa2p,
                                               float* __restrict__ deg) {
  __shared__ union {
    struct { _Float16 lA[NR * LSTR]; _Float16 lB[CT * LSTR]; float degp[4][16][33]; } p1;
    struct { _Float16 convT[NR * CTS]; _Float16 lB2[32 * BST2]; } p2;
  } S;

  int bid = blockIdx.x;                     // 256 blocks
  int d  = ((bid & 7) << 1) | ((bid >> 3) & 1);  // d-pair pinned per XCD slot
  int ct = bid >> 4;                        // 0..15
  int t = threadIdx.x;                      // 0..511
  int w = t >> 6;                           // 0..7
  int lane = t & 63;
  int l16 = lane & 15;
  int kg  = lane >> 4;
  int c0 = ct * CT;
  const float*    Adj = adjs + (size_t)d * NC2 * NL;   // as [2048][1024] row-major
  const _Float16* Gd  = G + (size_t)d * NR * NK;

  // ---------------- part 1: conv tile [96 x 128] ----------------
  f32x4 acc[6];
#pragma unroll
  for (int i = 0; i < 6; ++i) acc[i] = (f32x4)0.f;

  int brow = t >> 4;        // 0..31
  int col4 = t & 15;        // 0..15

  uint2  pa[3];             // prefetched A (G) regs
  float4 pb[4];             // prefetched B (adjs) regs

  auto loadA = [&](int kc) {
#pragma unroll
    for (int i = 0; i < 3; ++i) {
      int unit = i * 512 + t;
      int row = unit >> 4, u = unit & 15;
      pa[i] = *(const uint2*)(Gd + (size_t)row * NK + kc * KC + u * 4);
    }
  };
  auto loadB = [&](int kc) {
#pragma unroll
    for (int i = 0; i < 4; ++i) {
      int row = i * 32 + brow;
      pb[i] = *(const float4*)(Adj + (size_t)(c0 + row) * NK + kc * KC + col4 * 4);
    }
  };

  loadA(0);
  loadB(0);

  for (int kc = 0; kc < NK / KC; ++kc) {
    // write prefetched regs -> LDS (reg use = implicit per-wave vmcnt wait)
#pragma unroll
    for (int i = 0; i < 3; ++i) {
      int unit = i * 512 + t;
      int row = unit >> 4, u = unit & 15;
      *(uint2*)(&S.p1.lA[row * LSTR + u * 4]) = pa[i];
    }
    float cs0 = 0, cs1 = 0, cs2 = 0, cs3 = 0;
#pragma unroll
    for (int i = 0; i < 4; ++i) {
      int row = i * 32 + brow;
      float4 v = pb[i];
      cs0 += v.x; cs1 += v.y; cs2 += v.z; cs3 += v.w;
      half4v hv = {(_Float16)v.x, (_Float16)v.y, (_Float16)v.z, (_Float16)v.w};
      *(half4v*)(&S.p1.lB[row * LSTR + col4 * 4]) = hv;
    }
    S.p1.degp[0][col4][brow] = cs0;
    S.p1.degp[1][col4][brow] = cs1;
    S.p1.degp[2][col4][brow] = cs2;
    S.p1.degp[3][col4][brow] = cs3;
    // issue next chunk's loads; they stay in flight across both barriers + MFMA
    if (kc < NK / KC - 1) {
      loadA(kc + 1);
      loadB(kc + 1);
    }
    FENCE_BARRIER();
    if (t < 64) {
      int cg = t >> 2, ci = t & 3;
      float sum = 0.f;
#pragma unroll
      for (int p = 0; p < 32; ++p) sum += S.p1.degp[ci][cg][p];
      int j = kc * KC + cg * 4 + ci;
      atomicAdd(deg + d * NL + (j & (NL - 1)), sum);
    }
#pragma unroll
    for (int ks = 0; ks < 2; ++ks) {
      int ko = ks * 32 + 8 * kg;
      half8 b0 = *(const half8*)(&S.p1.lB[(w * 16 + l16) * LSTR + ko]);
#pragma unroll
      for (int mf = 0; mf < 6; ++mf) {
        half8 a = *(const half8*)(&S.p1.lA[(mf * 16 + l16) * LSTR + ko]);
        acc[mf] = __builtin_amdgcn_mfma_f32_16x16x32_f16(a, b0, acc[mf], 0, 0, 0);
      }
    }
    FENCE_BARRIER();
  }

  // conv tile -> LDS (c-contiguous rows for part-2 A-fragments)
#pragma unroll
  for (int mf = 0; mf < 6; ++mf)
#pragma unroll
    for (int jj = 0; jj < 4; ++jj) {
      int m  = mf * 16 + kg * 4 + jj;
      S.p2.convT[m * CTS + w * 16 + l16] = (_Float16)acc[mf][jj];
    }

  // ---------------- part 2: aa2 partial [96 x 512] over 128 c ----------------
  float4 pc[8];             // prefetched A0 regs
  auto loadC = [&](int cc2) {
#pragma unroll
    for (int i = 0; i < 8; ++i) {
      int unit = i * 512 + t;
      int c  = unit >> 7;         // 0..31
      int l4 = unit & 127;
      pc[i] = *(const float4*)(Adj + (size_t)(2 * (c0 + cc2 * 32 + c)) * NL + l4 * 4);
    }
  };
  loadC(0);                 // in flight across the convT barrier
  FENCE_BARRIER();

  f32x4 acc2[6][4];
#pragma unroll
  for (int i = 0; i < 6; ++i)
#pragma unroll
    for (int q = 0; q < 4; ++q) acc2[i][q] = (f32x4)0.f;

  for (int cc2 = 0; cc2 < 4; ++cc2) {
#pragma unroll
    for (int i = 0; i < 8; ++i) {
      int unit = i * 512 + t;
      int c  = unit >> 7;
      int l4 = unit & 127;
      float4 v = pc[i];
      half4v hv = {(_Float16)v.x, (_Float16)v.y, (_Float16)v.z, (_Float16)v.w};
      *(half4v*)(&S.p2.lB2[c * BST2 + l4 * 4]) = hv;
    }
    if (cc2 < 3) loadC(cc2 + 1);
    FENCE_BARRIER();
    half8 bfr[4];
#pragma unroll
    for (int nf = 0; nf < 4; ++nf) {
      int lcol = w * 64 + nf * 16 + l16;
#pragma unroll
      for (int j = 0; j < 8; ++j)
        bfr[nf][j] = S.p2.lB2[(kg * 8 + j) * BST2 + lcol];
    }
#pragma unroll
    for (int mf = 0; mf < 6; ++mf) {
      half8 a = *(const half8*)(&S.p2.convT[(mf * 16 + l16) * CTS + cc2 * 32 + kg * 8]);
#pragma unroll
      for (int nf = 0; nf < 4; ++nf)
        acc2[mf][nf] = __builtin_amdgcn_mfma_f32_16x16x32_f16(a, bfr[nf], acc2[mf][nf], 0, 0, 0);
    }
    FENCE_BARRIER();
  }
  _Float16* outp = aa2p + (size_t)(ct * ND + d) * NR * NL;
#pragma unroll
  for (int mf = 0; mf < 6; ++mf)
#pragma unroll
    for (int nf = 0; nf < 4; ++nf)
#pragma unroll
      for (int jj = 0; jj < 4; ++jj) {
        int m = mf * 16 + kg * 4 + jj;
        int l = w * 64 + nf * 16 + l16;
        outp[(size_t)m * NL + l] = (_Float16)acc2[mf][nf][jj];
      }
}

// ---------- Reduce: one block per (d, r): sum 16 partials, /deg, max over l
__global__ __launch_bounds__(256) void k_reduce(const _Float16* __restrict__ aa2p,
                                                const float* __restrict__ deg,
                                                float* __restrict__ dmax) {
  __shared__ float wm[4];
  int r = blockIdx.x;         // 0..95
  int d = blockIdx.y;         // 0..15
  int t = threadIdx.x;
  int w = t >> 6, lane = t & 63;
  float best = -1e30f;
#pragma unroll
  for (int rep = 0; rep < 2; ++rep) {
    int l = t + rep * 256;
    float s = 0.f;
#pragma unroll
    for (int ct = 0; ct < NCT; ++ct)
      s += (float)aa2p[((size_t)(ct * ND + d) * NR + r) * NL + l];
    best = fmaxf(best, s / deg[d * NL + l]);
  }
#pragma unroll
  for (int off = 32; off >= 1; off >>= 1)
    best = fmaxf(best, __shfl_xor(best, off));
  if (lane == 0) wm[w] = best;
  __syncthreads();
  if (t == 0)
    dmax[d * NR + r] = fmaxf(fmaxf(wm[0], wm[1]), fmaxf(wm[2], wm[3]));
}

// ---------- Out: 128 scores = dot(dmax row, lin_w) -> sigmoid
__global__ __launch_bounds__(128) void k_out(const float* __restrict__ dmax,
                                             const float* __restrict__ lin_w,
                                             float* __restrict__ out) {
  int t = threadIdx.x;        // 0..127: d = t>>3, b = t&7
  int d = t >> 3, b = t & 7;
  float s = 0.f;
#pragma unroll
  for (int f = 0; f < NF; ++f)
    s += dmax[d * NR + b * NF + f] * lin_w[f];
  out[d * NB + b] = 1.f / (1.f + expf(-s));
}

extern "C" void kernel_launch(void* const* d_in, const int* in_sizes, int n_in,
                              void* d_out, int out_size, void* d_ws, size_t ws_size,
                              hipStream_t stream) {
  const float* aa     = (const float*)d_in[0];
  const float* adjs   = (const float*)d_in[1];
  const float* conv_w = (const float*)d_in[2];
  const float* lin_w  = (const float*)d_in[3];
  float* out = (float*)d_out;

  char* ws = (char*)d_ws;
  _Float16* G    = (_Float16*)ws;                       // 3,145,728 B
  _Float16* aa2p = (_Float16*)(ws + 3145728);           // 16 fp16 partials: 25,165,824 B
  float*    deg  = (float*)(ws + 3145728 + 25165824);   // 32 KB
  float*    dmax = (float*)(ws + 3145728 + 25165824 + 32768); // 6 KB

  hipMemsetAsync(deg, 0, ND * NL * sizeof(float), stream);

  k_g<<<dim3((ND * NR * NK) / 256), 256, 0, stream>>>(aa, conv_w, G);
  k_fused<<<dim3(256), 512, 0, stream>>>(adjs, G, aa2p, deg);
  k_reduce<<<dim3(NR, ND), 256, 0, stream>>>(aa2p, deg, dmax);
  k_out<<<dim3(1), 128, 0, stream>>>(dmax, lin_w, out);
}